// Round 1
// baseline (200.561 us; speedup 1.0000x reference)
//
#include <hip/hip_runtime.h>
#include <hip/hip_fp16.h>

#define Mpts 32768
#define Vv 9
#define Cc 24
#define Hh 120
#define Ww 160
#define Npts (Mpts * 8)          // 262144
#define PIX (Hh * Ww)            // 19200
#define VOXEL 0.04f

// ---------------- workspace layout (bytes) ----------------
// [0,64)    : 3 doubles: sum_z, sum_z2, pos_cnt (zeroed by prep_tf)
// OFF_TF    : tf = feats (V,H,W) x 32B/pixel fp8(24ch+8pad) : 5529600 B
// OFF_PREH  : pre_h (M,24) f32                               : 3145728 B
// OFF_HP    : hp (12,N) uint (= half2 channel pairs)         : 12582912 B
// OFF_Z     : zbuf (N) f32                                   : 1048576 B
#define OFF_TF    64
#define OFF_PREH  (OFF_TF + Vv * PIX * 32)
#define OFF_HP    (OFF_PREH + Mpts * Cc * 4)
#define OFF_Z     (OFF_HP + Npts * Cc * 2)

typedef __attribute__((ext_vector_type(2))) float f32x2;

__device__ __forceinline__ unsigned pack2h(float a, float b) {
  __half2 h = __floats2half2_rn(a, b);
  return *(unsigned*)&h;
}

// pack 4 floats -> 4 fp8 e4m3 in one uint
__device__ __forceinline__ unsigned pack4fp8(float a, float b, float c,
                                             float d) {
  int u = __builtin_amdgcn_cvt_pk_fp8_f32(a, b, 0, false);
  u = __builtin_amdgcn_cvt_pk_fp8_f32(c, d, u, true);
  return (unsigned)u;
}

// ---------------- 1a) prep_tf: feats -> fp8 (V,H,W,32B), zero red ----------
__global__ __launch_bounds__(256) void prep_tf_kernel(
    const float* __restrict__ feats, uint4* __restrict__ tf,
    double* __restrict__ red) {
  __shared__ float tile[64][Cc + 1];
  int blk = blockIdx.x;
  if (blk == 0 && threadIdx.x < 3) red[threadIdx.x] = 0.0;

  int v = blk / 300;
  int p0 = (blk % 300) * 64;
  const float* src = feats + (size_t)v * (Cc * PIX);
  for (int i = threadIdx.x; i < Cc * 64; i += 256) {
    int c = i >> 6, p = i & 63;
    tile[p][c] = src[c * PIX + p0 + p];
  }
  __syncthreads();
  uint4* dst = tf + ((size_t)v * PIX + p0) * 2;
  if (threadIdx.x < 128) {
    int p = threadIdx.x >> 1, sel = threadIdx.x & 1;
    const float* t = &tile[p][0];
    uint4 u;
    if (sel == 0) {
      u.x = pack4fp8(t[0], t[1], t[2], t[3]);
      u.y = pack4fp8(t[4], t[5], t[6], t[7]);
      u.z = pack4fp8(t[8], t[9], t[10], t[11]);
      u.w = pack4fp8(t[12], t[13], t[14], t[15]);
    } else {
      u.x = pack4fp8(t[16], t[17], t[18], t[19]);
      u.y = pack4fp8(t[20], t[21], t[22], t[23]);
      u.z = 0;
      u.w = 0;
    }
    dst[p * 2 + sel] = u;
  }
}

// ---------------- 1b) prep_gemm: pre_h = pre_feat @ W_sp[25:75] + b --------
// LDS-staged: coalesced float4 global loads, LDS row reads (2-way = free).
__global__ __launch_bounds__(256) void prep_gemm_kernel(
    const float* __restrict__ pre_feat, const float* __restrict__ W_sp,
    const float* __restrict__ b_sp, float* __restrict__ pre_h) {
  __shared__ float P[256 * 50];   // 51200 B
  __shared__ float Wl[50 * Cc];   // 4800 B
  __shared__ float bl[Cc];
  int blk = blockIdx.x;
  const float4* src4 = (const float4*)(pre_feat + (size_t)blk * (256 * 50));
  for (int i = threadIdx.x; i < (256 * 50) / 4; i += 256)
    ((float4*)P)[i] = src4[i];
  for (int i = threadIdx.x; i < 50 * Cc; i += 256) Wl[i] = W_sp[25 * Cc + i];
  if (threadIdx.x < Cc) bl[threadIdx.x] = b_sp[threadIdx.x];
  __syncthreads();

  float acc[Cc];
#pragma unroll
  for (int j = 0; j < Cc; j++) acc[j] = bl[j];
  const float2* row = (const float2*)&P[threadIdx.x * 50];
#pragma unroll
  for (int k = 0; k < 25; k++) {
    float2 x = row[k];
#pragma unroll
    for (int j = 0; j < Cc; j++)
      acc[j] += x.x * Wl[(2 * k) * Cc + j] + x.y * Wl[(2 * k + 1) * Cc + j];
  }
  float4* o4 = (float4*)(pre_h + ((size_t)blk * 256 + threadIdx.x) * Cc);
  o4[0] = make_float4(acc[0], acc[1], acc[2], acc[3]);
  o4[1] = make_float4(acc[4], acc[5], acc[6], acc[7]);
  o4[2] = make_float4(acc[8], acc[9], acc[10], acc[11]);
  o4[3] = make_float4(acc[12], acc[13], acc[14], acc[15]);
  o4[4] = make_float4(acc[16], acc[17], acc[18], acc[19]);
  o4[5] = make_float4(acc[20], acc[21], acc[22], acc[23]);
}

// acc[0..15] += w * fp8x16(A)
__device__ __forceinline__ void acc16(uint4 A, float w, float* acc) {
#pragma unroll
  for (int t = 0; t < 4; t++) {
    unsigned u = ((const unsigned*)&A)[t];
    f32x2 f0 = __builtin_amdgcn_cvt_pk_f32_fp8((int)u, false);
    f32x2 f1 = __builtin_amdgcn_cvt_pk_f32_fp8((int)u, true);
    acc[4 * t + 0] += w * f0.x;
    acc[4 * t + 1] += w * f0.y;
    acc[4 * t + 2] += w * f1.x;
    acc[4 * t + 3] += w * f1.y;
  }
}
// acc[0..7] += w * fp8x8(ux,uy)
__device__ __forceinline__ void acc8v(unsigned ux, unsigned uy, float w,
                                      float* acc) {
  f32x2 f0 = __builtin_amdgcn_cvt_pk_f32_fp8((int)ux, false);
  f32x2 f1 = __builtin_amdgcn_cvt_pk_f32_fp8((int)ux, true);
  f32x2 f2 = __builtin_amdgcn_cvt_pk_f32_fp8((int)uy, false);
  f32x2 f3 = __builtin_amdgcn_cvt_pk_f32_fp8((int)uy, true);
  acc[0] += w * f0.x;
  acc[1] += w * f0.y;
  acc[2] += w * f1.x;
  acc[3] += w * f1.y;
  acc[4] += w * f2.x;
  acc[5] += w * f2.y;
  acc[6] += w * f3.x;
  acc[7] += w * f3.y;
}

// ---------------- 2) main: 2 lanes per point, views split by parity --------
// Even lane of a pair handles views 0,2,4,6,8; odd lane 1,3,5,7.
// Partial acc/zsum/cnt combined via shfl_xor(1); h-GEMM done redundantly
// on both lanes (wave-uniform W_sp scalar loads); hp writes split by parity.
__global__ __launch_bounds__(256) void main_kernel(
    const int* __restrict__ pre_coords, const uint4* __restrict__ tfq,
    const float* __restrict__ KRcam, const float* __restrict__ vol_origin,
    const float* __restrict__ w2ac, const float* __restrict__ W_sp,
    const float* __restrict__ pre_h, float* __restrict__ out,
    unsigned* __restrict__ hp, float* __restrict__ zbuf,
    double* __restrict__ red) {
  __shared__ float KR[Vv * 12];
  __shared__ float w2a[12];
  __shared__ float orig[3];
  __shared__ float redl[3][4];
  for (int i = threadIdx.x; i < Vv * 12; i += 256) {
    int v = i / 12, r = i - v * 12;
    KR[i] = KRcam[v * 16 + r];
  }
  if (threadIdx.x < 12) w2a[threadIdx.x] = w2ac[threadIdx.x];
  if (threadIdx.x < 3) orig[threadIdx.x] = vol_origin[threadIdx.x];
  __syncthreads();

  int g = blockIdx.x * 256 + threadIdx.x;
  int n = g >> 1;          // point index
  int q = g & 1;           // pair parity (view subset / write subset)
  int m = n >> 3, o = n & 7;
  int4 pc = ((const int4*)pre_coords)[m];
  int cx = pc.y + ((0xB2 >> o) & 1);
  int cy = pc.z + ((0xD4 >> o) & 1);
  int cz = pc.w + ((0xE8 >> o) & 1);
  float wx0 = (float)cx * VOXEL + orig[0];
  float wy0 = (float)cy * VOXEL + orig[1];
  float wz0 = (float)cz * VOXEL + orig[2];

  if (q == 0) {  // r_coords (one write per point)
    float camx = w2a[0] * wx0 + w2a[1] * wy0 + w2a[2] * wz0 + w2a[3];
    float camy = w2a[4] * wx0 + w2a[5] * wy0 + w2a[6] * wz0 + w2a[7];
    float camz = w2a[8] * wx0 + w2a[9] * wy0 + w2a[10] * wz0 + w2a[11];
    float4 rc = make_float4(camx, camy, camz, (float)pc.x);
    ((float4*)(out + 3 * (size_t)Npts))[n] = rc;
  }

  float acc[Cc];
#pragma unroll
  for (int c = 0; c < Cc; c++) acc[c] = 0.f;
  float zsum = 0.f;
  int cnt = 0;

  for (int v = q; v < Vv; v += 2) {
    const float* kr = &KR[v * 12];
    float ix = kr[0] * wx0 + kr[1] * wy0 + kr[2] * wz0 + kr[3];
    float iy = kr[4] * wx0 + kr[5] * wy0 + kr[6] * wz0 + kr[7];
    float iz = kr[8] * wx0 + kr[9] * wy0 + kr[10] * wz0 + kr[11];
    float sz = (fabsf(iz) > 1e-9f) ? iz : 1e-9f;
    float px = ix / sz;
    float py = iy / sz;
    bool msk = (px >= 0.f) && (px <= (float)(Ww - 1)) && (py >= 0.f) &&
               (py <= (float)(Hh - 1)) && (iz > 0.f);
    if (msk) {
      int x0 = (int)floorf(px), y0 = (int)floorf(py);
      int xs = min(x0, Ww - 2), ys = min(y0, Hh - 2);
      float wx = px - (float)xs, wy = py - (float)ys;
      float w00 = (1.f - wx) * (1.f - wy);
      float w10 = wx * (1.f - wy);
      float w01 = (1.f - wx) * wy;
      float w11 = wx * wy;
      const uint4* p = tfq + ((size_t)(v * PIX + ys * Ww + xs)) * 2;
      const uint4* qr = p + Ww * 2;
      uint4 A = p[0], Ab = p[1], B = p[2], Bb = p[3];
      uint4 C = qr[0], Cb = qr[1], D = qr[2], Db = qr[3];
      acc16(A, w00, &acc[0]);
      acc8v(Ab.x, Ab.y, w00, &acc[16]);
      acc16(B, w10, &acc[0]);
      acc8v(Bb.x, Bb.y, w10, &acc[16]);
      acc16(C, w01, &acc[0]);
      acc8v(Cb.x, Cb.y, w01, &acc[16]);
      acc16(D, w11, &acc[0]);
      acc8v(Db.x, Db.y, w11, &acc[16]);
      zsum += iz;
      cnt++;
    }
  }

  // ---- pair combine (lanes 2i / 2i+1 hold partials of the same point) ----
  zsum += __shfl_xor(zsum, 1);
  int ct = cnt + __shfl_xor(cnt, 1);
#pragma unroll
  for (int c = 0; c < Cc; c++) acc[c] += __shfl_xor(acc[c], 1);

  float denom = fmaxf((float)ct, 1.f);
  float invd = 1.f / denom;
  float z = zsum * invd;

  // h = (acc*invd) @ W_sp[0:24,:]  (redundant on both lanes; W_sp offsets are
  // thread-uniform compile-time constants -> scalar loads)
  float h[Cc];
#pragma unroll
  for (int j = 0; j < Cc; j++) h[j] = 0.f;
#pragma unroll
  for (int c = 0; c < Cc; c++) {
    float f = acc[c] * invd;
#pragma unroll
    for (int j = 0; j < Cc; j++) h[j] += f * W_sp[c * Cc + j];
  }

  // pre_h split by parity: even lane ch 0..11, odd lane ch 12..23
  const float4* ph4 = (const float4*)(pre_h + (size_t)m * Cc + q * 12);
  float4 pa = ph4[0], pb = ph4[1], pcv = ph4[2];
  float phv[12] = {pa.x, pa.y, pa.z, pa.w,  pb.x,  pb.y,
                   pb.z, pb.w, pcv.x, pcv.y, pcv.z, pcv.w};

  if (q == 0) {
#pragma unroll
    for (int j2 = 0; j2 < 6; j2++)
      hp[(size_t)j2 * Npts + n] =
          pack2h(h[2 * j2] + phv[2 * j2], h[2 * j2 + 1] + phv[2 * j2 + 1]);
  } else {
#pragma unroll
    for (int j2 = 0; j2 < 6; j2++)
      hp[(size_t)(6 + j2) * Npts + n] = pack2h(h[12 + 2 * j2] + phv[2 * j2],
                                               h[13 + 2 * j2] + phv[2 * j2 + 1]);
  }

  if (q == 0) {
    zbuf[n] = z;
    out[2 * (size_t)Npts + n] = (float)ct;
  }

  // reduction for zmean / znorm (count each point once: even lanes only)
  float rz = (q == 0 && z > 0.f) ? z : 0.f;
  float rz2 = rz * rz;
  float rcn = (q == 0 && z > 0.f) ? 1.f : 0.f;
#pragma unroll
  for (int off = 32; off > 0; off >>= 1) {
    rz += __shfl_down(rz, off);
    rz2 += __shfl_down(rz2, off);
    rcn += __shfl_down(rcn, off);
  }
  int wid = threadIdx.x >> 6, lid = threadIdx.x & 63;
  if (lid == 0) {
    redl[0][wid] = rz;
    redl[1][wid] = rz2;
    redl[2][wid] = rcn;
  }
  __syncthreads();
  if (threadIdx.x == 0) {
    float a = 0.f, b = 0.f, c = 0.f;
#pragma unroll
    for (int w = 0; w < 4; w++) {
      a += redl[0][w];
      b += redl[1][w];
      c += redl[2][w];
    }
    atomicAdd(&red[0], (double)a);
    atomicAdd(&red[1], (double)b);
    atomicAdd(&red[2], (double)c);
  }
}

// ---------------- 3) finalize: zn + relu + heads ---------------------------
__global__ __launch_bounds__(256) void final_kernel(
    const float* __restrict__ zbuf, const unsigned* __restrict__ hp,
    const float* __restrict__ W_sp, const float* __restrict__ W_t,
    const float* __restrict__ b_t, const float* __restrict__ W_o,
    const float* __restrict__ b_o, const double* __restrict__ red,
    float* __restrict__ out) {
  __shared__ float wz[Cc], wt[Cc], wo[Cc];
  __shared__ float bt, bo, s_zmean, s_izn;
  if (threadIdx.x < Cc) {
    wz[threadIdx.x] = W_sp[24 * Cc + threadIdx.x];
    wt[threadIdx.x] = W_t[threadIdx.x];
    wo[threadIdx.x] = W_o[threadIdx.x];
  }
  if (threadIdx.x == 0) {
    bt = b_t[0];
    bo = b_o[0];
    double sz = red[0], sz2 = red[1], cd = red[2];
    double npos = (cd > 0.0) ? cd : 1.0;
    double zmean = sz / npos;
    double var = sz2 - 2.0 * zmean * sz + cd * zmean * zmean;
    if (var < 0.0) var = 0.0;
    double znorm = sqrt(var) + 1e-5;
    s_zmean = (float)zmean;
    s_izn = (float)(1.0 / znorm);
  }
  __syncthreads();
  int n = blockIdx.x * 256 + threadIdx.x;
  float z = zbuf[n];
  float zn = (z > 0.f) ? (z - s_zmean) * s_izn : 0.f;
  float tsdf = bt, occ = bo;
#pragma unroll
  for (int j2 = 0; j2 < 12; j2++) {
    unsigned u = hp[(size_t)j2 * Npts + n];
    float2 f = __half22float2(*(const __half2*)&u);
    float h0 = fmaxf(f.x + zn * wz[2 * j2], 0.f);
    float h1 = fmaxf(f.y + zn * wz[2 * j2 + 1], 0.f);
    tsdf += h0 * wt[2 * j2] + h1 * wt[2 * j2 + 1];
    occ += h0 * wo[2 * j2] + h1 * wo[2 * j2 + 1];
  }
  ((float2*)out)[n] = make_float2(tsdf, occ);
}

// ---------------- launch ---------------------------------------------------
extern "C" void kernel_launch(void* const* d_in, const int* in_sizes, int n_in,
                              void* d_out, int out_size, void* d_ws,
                              size_t ws_size, hipStream_t stream) {
  const float* pre_feat = (const float*)d_in[0];
  const int* pre_coords = (const int*)d_in[1];
  const float* feats = (const float*)d_in[2];
  const float* KRcam = (const float*)d_in[3];
  const float* vol_origin = (const float*)d_in[4];
  const float* w2ac = (const float*)d_in[5];
  const float* W_sp = (const float*)d_in[6];
  const float* b_sp = (const float*)d_in[7];
  const float* W_t = (const float*)d_in[8];
  const float* b_t = (const float*)d_in[9];
  const float* W_o = (const float*)d_in[10];
  const float* b_o = (const float*)d_in[11];

  float* out = (float*)d_out;
  char* ws = (char*)d_ws;
  double* red = (double*)ws;
  uint4* tf = (uint4*)(ws + OFF_TF);
  float* pre_h = (float*)(ws + OFF_PREH);
  unsigned* hp = (unsigned*)(ws + OFF_HP);
  float* zbuf = (float*)(ws + OFF_Z);

  prep_tf_kernel<<<Vv * 300, 256, 0, stream>>>(feats, tf, red);
  prep_gemm_kernel<<<Mpts / 256, 256, 0, stream>>>(pre_feat, W_sp, b_sp,
                                                   pre_h);
  main_kernel<<<(2 * Npts) / 256, 256, 0, stream>>>(pre_coords, tf, KRcam,
                                                    vol_origin, w2ac, W_sp,
                                                    pre_h, out, hp, zbuf, red);
  final_kernel<<<Npts / 256, 256, 0, stream>>>(zbuf, hp, W_sp, W_t, b_t, W_o,
                                               b_o, red, out);
}

// Round 2
// 171.101 us; speedup vs baseline: 1.1722x; 1.1722x over previous
//
#include <hip/hip_runtime.h>
#include <hip/hip_fp16.h>

#define Mpts 32768
#define Vv 9
#define Cc 24
#define Hh 120
#define Ww 160
#define Npts (Mpts * 8)          // 262144
#define PIX (Hh * Ww)            // 19200
#define VOXEL 0.04f

// ---------------- workspace layout (bytes) ----------------
// [0,64)    : 3 doubles: sum_z, sum_z2, pos_cnt (zeroed by prep_tf)
// OFF_TF    : tf = feats (V,H,W) x 32B/pixel fp8(24ch+8pad) : 5529600 B
// OFF_PREH  : pre_h (M,24) f32                               : 3145728 B
// OFF_HP    : hp (12,N) uint (= half2 channel pairs)         : 12582912 B
// OFF_Z     : zbuf (N) f32                                   : 1048576 B
#define OFF_TF    64
#define OFF_PREH  (OFF_TF + Vv * PIX * 32)
#define OFF_HP    (OFF_PREH + Mpts * Cc * 4)
#define OFF_Z     (OFF_HP + Npts * Cc * 2)

typedef __attribute__((ext_vector_type(2))) float f32x2;

__device__ __forceinline__ unsigned pack2h(float a, float b) {
  __half2 h = __floats2half2_rn(a, b);
  return *(unsigned*)&h;
}

// pack 4 floats -> 4 fp8 e4m3 in one uint
__device__ __forceinline__ unsigned pack4fp8(float a, float b, float c,
                                             float d) {
  int u = __builtin_amdgcn_cvt_pk_fp8_f32(a, b, 0, false);
  u = __builtin_amdgcn_cvt_pk_fp8_f32(c, d, u, true);
  return (unsigned)u;
}

// ---------------- 1a) prep_tf: feats -> fp8 (V,H,W,32B), zero red ----------
__global__ __launch_bounds__(256) void prep_tf_kernel(
    const float* __restrict__ feats, uint4* __restrict__ tf,
    double* __restrict__ red) {
  __shared__ float tile[64][Cc + 1];
  int blk = blockIdx.x;
  if (blk == 0 && threadIdx.x < 3) red[threadIdx.x] = 0.0;

  int v = blk / 300;
  int p0 = (blk % 300) * 64;
  const float* src = feats + (size_t)v * (Cc * PIX);
  for (int i = threadIdx.x; i < Cc * 64; i += 256) {
    int c = i >> 6, p = i & 63;
    tile[p][c] = src[c * PIX + p0 + p];
  }
  __syncthreads();
  uint4* dst = tf + ((size_t)v * PIX + p0) * 2;
  if (threadIdx.x < 128) {
    int p = threadIdx.x >> 1, sel = threadIdx.x & 1;
    const float* t = &tile[p][0];
    uint4 u;
    if (sel == 0) {
      u.x = pack4fp8(t[0], t[1], t[2], t[3]);
      u.y = pack4fp8(t[4], t[5], t[6], t[7]);
      u.z = pack4fp8(t[8], t[9], t[10], t[11]);
      u.w = pack4fp8(t[12], t[13], t[14], t[15]);
    } else {
      u.x = pack4fp8(t[16], t[17], t[18], t[19]);
      u.y = pack4fp8(t[20], t[21], t[22], t[23]);
      u.z = 0;
      u.w = 0;
    }
    dst[p * 2 + sel] = u;
  }
}

// ---------------- 1b) prep_gemm: pre_h = pre_feat @ W_sp[25:75] + b --------
__global__ __launch_bounds__(256) void prep_gemm_kernel(
    const float* __restrict__ pre_feat, const float* __restrict__ W_sp,
    const float* __restrict__ b_sp, float* __restrict__ pre_h) {
  __shared__ float P[256 * 50];   // 51200 B
  __shared__ float Wl[50 * Cc];   // 4800 B
  __shared__ float bl[Cc];
  int blk = blockIdx.x;
  const float4* src4 = (const float4*)(pre_feat + (size_t)blk * (256 * 50));
  for (int i = threadIdx.x; i < (256 * 50) / 4; i += 256)
    ((float4*)P)[i] = src4[i];
  for (int i = threadIdx.x; i < 50 * Cc; i += 256) Wl[i] = W_sp[25 * Cc + i];
  if (threadIdx.x < Cc) bl[threadIdx.x] = b_sp[threadIdx.x];
  __syncthreads();

  float acc[Cc];
#pragma unroll
  for (int j = 0; j < Cc; j++) acc[j] = bl[j];
  const float2* row = (const float2*)&P[threadIdx.x * 50];
#pragma unroll
  for (int k = 0; k < 25; k++) {
    float2 x = row[k];
#pragma unroll
    for (int j = 0; j < Cc; j++)
      acc[j] += x.x * Wl[(2 * k) * Cc + j] + x.y * Wl[(2 * k + 1) * Cc + j];
  }
  float4* o4 = (float4*)(pre_h + ((size_t)blk * 256 + threadIdx.x) * Cc);
  o4[0] = make_float4(acc[0], acc[1], acc[2], acc[3]);
  o4[1] = make_float4(acc[4], acc[5], acc[6], acc[7]);
  o4[2] = make_float4(acc[8], acc[9], acc[10], acc[11]);
  o4[3] = make_float4(acc[12], acc[13], acc[14], acc[15]);
  o4[4] = make_float4(acc[16], acc[17], acc[18], acc[19]);
  o4[5] = make_float4(acc[20], acc[21], acc[22], acc[23]);
}

// acc[0..15] += w * fp8x16(A)
__device__ __forceinline__ void acc16(uint4 A, float w, float* acc) {
#pragma unroll
  for (int t = 0; t < 4; t++) {
    unsigned u = ((const unsigned*)&A)[t];
    f32x2 f0 = __builtin_amdgcn_cvt_pk_f32_fp8((int)u, false);
    f32x2 f1 = __builtin_amdgcn_cvt_pk_f32_fp8((int)u, true);
    acc[4 * t + 0] += w * f0.x;
    acc[4 * t + 1] += w * f0.y;
    acc[4 * t + 2] += w * f1.x;
    acc[4 * t + 3] += w * f1.y;
  }
}
// acc[0..7] += w * fp8x8(ux,uy)
__device__ __forceinline__ void acc8v(unsigned ux, unsigned uy, float w,
                                      float* acc) {
  f32x2 f0 = __builtin_amdgcn_cvt_pk_f32_fp8((int)ux, false);
  f32x2 f1 = __builtin_amdgcn_cvt_pk_f32_fp8((int)ux, true);
  f32x2 f2 = __builtin_amdgcn_cvt_pk_f32_fp8((int)uy, false);
  f32x2 f3 = __builtin_amdgcn_cvt_pk_f32_fp8((int)uy, true);
  acc[0] += w * f0.x;
  acc[1] += w * f0.y;
  acc[2] += w * f1.x;
  acc[3] += w * f1.y;
  acc[4] += w * f2.x;
  acc[5] += w * f2.y;
  acc[6] += w * f3.x;
  acc[7] += w * f3.y;
}

// ---------------- main: 1 thread/point, depth-2 software-pipelined views ---
// View loop is made control-flow-uniform (masked lanes gather pixel 0 with
// zero weights -- exec-masked VALU issued anyway, so this is free) so that
// view k+1 / k+2 gathers stay in flight while view k accumulates.
struct VState {
  const uint4* p;          // row0 corner0 pixel base
  float w00, w10, w01, w11;
  float izm;               // iz if masked-in else 0
  int mski;                // 1 if masked-in
};

__device__ __forceinline__ VState project(int v, const float* KR,
                                          const uint4* tfq, float wx0,
                                          float wy0, float wz0) {
  const float* kr = &KR[v * 12];
  float ix = kr[0] * wx0 + kr[1] * wy0 + kr[2] * wz0 + kr[3];
  float iy = kr[4] * wx0 + kr[5] * wy0 + kr[6] * wz0 + kr[7];
  float iz = kr[8] * wx0 + kr[9] * wy0 + kr[10] * wz0 + kr[11];
  float sz = (fabsf(iz) > 1e-9f) ? iz : 1e-9f;
  float rs = 1.f / sz;
  float px = ix * rs;
  float py = iy * rs;
  bool msk = (px >= 0.f) && (px <= (float)(Ww - 1)) && (py >= 0.f) &&
             (py <= (float)(Hh - 1)) && (iz > 0.f);
  float pxc = fminf(fmaxf(px, 0.f), (float)(Ww - 1));
  float pyc = fminf(fmaxf(py, 0.f), (float)(Hh - 1));
  int xs = min((int)pxc, Ww - 2);
  int ys = min((int)pyc, Hh - 2);
  float wx = pxc - (float)xs, wy = pyc - (float)ys;
  float wm = msk ? 1.f : 0.f;
  float u = 1.f - wx, t = 1.f - wy;
  VState s;
  s.w00 = u * t * wm;
  s.w10 = wx * t * wm;
  s.w01 = u * wy * wm;
  s.w11 = wx * wy * wm;
  int pix = msk ? (ys * Ww + xs) : 0;
  s.p = tfq + ((size_t)(v * PIX + pix)) * 2;
  s.izm = msk ? iz : 0.f;
  s.mski = msk ? 1 : 0;
  return s;
}

struct GBuf {
  uint4 A0, A1, B0, B1;    // ch0-15 of the 4 bilinear corners
  uint2 A0b, A1b, B0b, B1b;  // ch16-23
};

__device__ __forceinline__ GBuf gload(const VState& s) {
  GBuf g;
  const uint4* p = s.p;
  const uint4* q = p + Ww * 2;  // next image row
  g.A0 = p[0];
  g.A0b = *(const uint2*)(p + 1);
  g.A1 = p[2];
  g.A1b = *(const uint2*)(p + 3);
  g.B0 = q[0];
  g.B0b = *(const uint2*)(q + 1);
  g.B1 = q[2];
  g.B1b = *(const uint2*)(q + 3);
  return g;
}

__device__ __forceinline__ void gacc(const GBuf& g, const VState& s,
                                     float* acc) {
  acc16(g.A0, s.w00, acc);
  acc8v(g.A0b.x, g.A0b.y, s.w00, acc + 16);
  acc16(g.A1, s.w10, acc);
  acc8v(g.A1b.x, g.A1b.y, s.w10, acc + 16);
  acc16(g.B0, s.w01, acc);
  acc8v(g.B0b.x, g.B0b.y, s.w01, acc + 16);
  acc16(g.B1, s.w11, acc);
  acc8v(g.B1b.x, g.B1b.y, s.w11, acc + 16);
}

__global__ __launch_bounds__(256, 4) void main_kernel(
    const int* __restrict__ pre_coords, const uint4* __restrict__ tfq,
    const float* __restrict__ KRcam, const float* __restrict__ vol_origin,
    const float* __restrict__ w2ac, const float* __restrict__ W_sp,
    const float* __restrict__ pre_h, float* __restrict__ out,
    unsigned* __restrict__ hp, float* __restrict__ zbuf,
    double* __restrict__ red) {
  __shared__ float KR[Vv * 12];
  __shared__ float w2a[12];
  __shared__ float orig[3];
  __shared__ float redl[3][4];
  for (int i = threadIdx.x; i < Vv * 12; i += 256) {
    int v = i / 12, r = i - v * 12;
    KR[i] = KRcam[v * 16 + r];
  }
  if (threadIdx.x < 12) w2a[threadIdx.x] = w2ac[threadIdx.x];
  if (threadIdx.x < 3) orig[threadIdx.x] = vol_origin[threadIdx.x];
  __syncthreads();

  int n = blockIdx.x * 256 + threadIdx.x;
  int m = n >> 3, o = n & 7;
  int4 pc = ((const int4*)pre_coords)[m];
  int cx = pc.y + ((0xB2 >> o) & 1);
  int cy = pc.z + ((0xD4 >> o) & 1);
  int cz = pc.w + ((0xE8 >> o) & 1);
  float wx0 = (float)cx * VOXEL + orig[0];
  float wy0 = (float)cy * VOXEL + orig[1];
  float wz0 = (float)cz * VOXEL + orig[2];

  {  // r_coords
    float camx = w2a[0] * wx0 + w2a[1] * wy0 + w2a[2] * wz0 + w2a[3];
    float camy = w2a[4] * wx0 + w2a[5] * wy0 + w2a[6] * wz0 + w2a[7];
    float camz = w2a[8] * wx0 + w2a[9] * wy0 + w2a[10] * wz0 + w2a[11];
    float4 rc = make_float4(camx, camy, camz, (float)pc.x);
    ((float4*)(out + 3 * (size_t)Npts))[n] = rc;
  }

  float acc[Cc];
#pragma unroll
  for (int c = 0; c < Cc; c++) acc[c] = 0.f;
  float zsum = 0.f;
  int cnt = 0;

  // ---- depth-2 pipelined view loop (fully unrolled; static buffer idx) ----
  VState st[2];
  GBuf gb[2];
  st[0] = project(0, KR, tfq, wx0, wy0, wz0);
  gb[0] = gload(st[0]);
  st[1] = project(1, KR, tfq, wx0, wy0, wz0);
  gb[1] = gload(st[1]);
#pragma unroll
  for (int k = 0; k < Vv; k++) {
    int b = k & 1;
    gacc(gb[b], st[b], acc);
    zsum += st[b].izm;
    cnt += st[b].mski;
    if (k + 2 < Vv) {
      st[b] = project(k + 2, KR, tfq, wx0, wy0, wz0);
      gb[b] = gload(st[b]);
    }
  }

  float denom = fmaxf((float)cnt, 1.f);
  float invd = 1.f / denom;
  float z = zsum * invd;

  // h = pre_h[m] + (acc*invd) @ W_sp[0:24,:]  (W_sp: uniform scalar loads)
  float h[Cc];
  const float* ph = pre_h + (size_t)m * Cc;
#pragma unroll
  for (int j = 0; j < Cc; j++) h[j] = ph[j];
#pragma unroll
  for (int c = 0; c < Cc; c++) {
    float f = acc[c] * invd;
#pragma unroll
    for (int j = 0; j < Cc; j++) h[j] += f * W_sp[c * Cc + j];
  }
#pragma unroll
  for (int j2 = 0; j2 < 12; j2++)
    hp[(size_t)j2 * Npts + n] = pack2h(h[2 * j2], h[2 * j2 + 1]);

  zbuf[n] = z;
  out[2 * (size_t)Npts + n] = (float)cnt;

  // reduction for zmean / znorm
  float rz = (z > 0.f) ? z : 0.f;
  float rz2 = rz * rz;
  float rcn = (z > 0.f) ? 1.f : 0.f;
#pragma unroll
  for (int off = 32; off > 0; off >>= 1) {
    rz += __shfl_down(rz, off);
    rz2 += __shfl_down(rz2, off);
    rcn += __shfl_down(rcn, off);
  }
  int wid = threadIdx.x >> 6, lid = threadIdx.x & 63;
  if (lid == 0) {
    redl[0][wid] = rz;
    redl[1][wid] = rz2;
    redl[2][wid] = rcn;
  }
  __syncthreads();
  if (threadIdx.x == 0) {
    float a = 0.f, b = 0.f, c = 0.f;
#pragma unroll
    for (int w = 0; w < 4; w++) {
      a += redl[0][w];
      b += redl[1][w];
      c += redl[2][w];
    }
    atomicAdd(&red[0], (double)a);
    atomicAdd(&red[1], (double)b);
    atomicAdd(&red[2], (double)c);
  }
}

// ---------------- 3) finalize: zn + relu + heads ---------------------------
__global__ __launch_bounds__(256) void final_kernel(
    const float* __restrict__ zbuf, const unsigned* __restrict__ hp,
    const float* __restrict__ W_sp, const float* __restrict__ W_t,
    const float* __restrict__ b_t, const float* __restrict__ W_o,
    const float* __restrict__ b_o, const double* __restrict__ red,
    float* __restrict__ out) {
  __shared__ float wz[Cc], wt[Cc], wo[Cc];
  __shared__ float bt, bo, s_zmean, s_izn;
  if (threadIdx.x < Cc) {
    wz[threadIdx.x] = W_sp[24 * Cc + threadIdx.x];
    wt[threadIdx.x] = W_t[threadIdx.x];
    wo[threadIdx.x] = W_o[threadIdx.x];
  }
  if (threadIdx.x == 0) {
    bt = b_t[0];
    bo = b_o[0];
    double sz = red[0], sz2 = red[1], cd = red[2];
    double npos = (cd > 0.0) ? cd : 1.0;
    double zmean = sz / npos;
    double var = sz2 - 2.0 * zmean * sz + cd * zmean * zmean;
    if (var < 0.0) var = 0.0;
    double znorm = sqrt(var) + 1e-5;
    s_zmean = (float)zmean;
    s_izn = (float)(1.0 / znorm);
  }
  __syncthreads();
  int n = blockIdx.x * 256 + threadIdx.x;
  float z = zbuf[n];
  float zn = (z > 0.f) ? (z - s_zmean) * s_izn : 0.f;
  float tsdf = bt, occ = bo;
#pragma unroll
  for (int j2 = 0; j2 < 12; j2++) {
    unsigned u = hp[(size_t)j2 * Npts + n];
    float2 f = __half22float2(*(const __half2*)&u);
    float h0 = fmaxf(f.x + zn * wz[2 * j2], 0.f);
    float h1 = fmaxf(f.y + zn * wz[2 * j2 + 1], 0.f);
    tsdf += h0 * wt[2 * j2] + h1 * wt[2 * j2 + 1];
    occ += h0 * wo[2 * j2] + h1 * wo[2 * j2 + 1];
  }
  ((float2*)out)[n] = make_float2(tsdf, occ);
}

// ---------------- launch ---------------------------------------------------
extern "C" void kernel_launch(void* const* d_in, const int* in_sizes, int n_in,
                              void* d_out, int out_size, void* d_ws,
                              size_t ws_size, hipStream_t stream) {
  const float* pre_feat = (const float*)d_in[0];
  const int* pre_coords = (const int*)d_in[1];
  const float* feats = (const float*)d_in[2];
  const float* KRcam = (const float*)d_in[3];
  const float* vol_origin = (const float*)d_in[4];
  const float* w2ac = (const float*)d_in[5];
  const float* W_sp = (const float*)d_in[6];
  const float* b_sp = (const float*)d_in[7];
  const float* W_t = (const float*)d_in[8];
  const float* b_t = (const float*)d_in[9];
  const float* W_o = (const float*)d_in[10];
  const float* b_o = (const float*)d_in[11];

  float* out = (float*)d_out;
  char* ws = (char*)d_ws;
  double* red = (double*)ws;
  uint4* tf = (uint4*)(ws + OFF_TF);
  float* pre_h = (float*)(ws + OFF_PREH);
  unsigned* hp = (unsigned*)(ws + OFF_HP);
  float* zbuf = (float*)(ws + OFF_Z);

  prep_tf_kernel<<<Vv * 300, 256, 0, stream>>>(feats, tf, red);
  prep_gemm_kernel<<<Mpts / 256, 256, 0, stream>>>(pre_feat, W_sp, b_sp,
                                                   pre_h);
  main_kernel<<<Npts / 256, 256, 0, stream>>>(pre_coords, tf, KRcam,
                                              vol_origin, w2ac, W_sp, pre_h,
                                              out, hp, zbuf, red);
  final_kernel<<<Npts / 256, 256, 0, stream>>>(zbuf, hp, W_sp, W_t, b_t, W_o,
                                               b_o, red, out);
}